// Round 1
// 713.579 us; speedup vs baseline: 1.0224x; 1.0224x over previous
//
#include <hip/hip_runtime.h>

#define B_ 4
#define N_ 4096
#define D_ 2048
#define E_ 8
#define R_ 128
#define K_ 1024

typedef __attribute__((ext_vector_type(8))) short bf16x8;
typedef __attribute__((ext_vector_type(4))) float f32x4;

__device__ inline unsigned short f2bf(float f) {
  unsigned u = __float_as_uint(f);
  unsigned r = (u + 0x7FFFu + ((u >> 16) & 1u)) >> 16;  // RNE
  return (unsigned short)r;
}

// ---------------------------------------------------------------------------
// Gate logits (fp32 — top-k boundary gaps ~1e-3 require fp32 precision here)
// FUSED with x->bf16 conversion (x is streamed here anyway; saves a full
// 134MB re-read pass that cvt_x_kernel used to do).
// One wave per token, lanes stride D in float4. Writes logitsT[b][e][n].
// ---------------------------------------------------------------------------
__global__ __launch_bounds__(256) void gate_kernel(const float* __restrict__ x,
                                                   const float* __restrict__ Wg,
                                                   const float* __restrict__ bg,
                                                   float* __restrict__ logitsT,
                                                   unsigned short* __restrict__ xbf) {
  int wave = threadIdx.x >> 6;
  int lane = threadIdx.x & 63;
  int token = blockIdx.x * 4 + wave;
  int b = token >> 12;          // token / N_
  int n = token & (N_ - 1);     // token % N_
  const float* xr = x + (size_t)token * D_;
  unsigned short* xbr = xbf + (size_t)token * D_;
  float acc[E_];
#pragma unroll
  for (int e = 0; e < E_; ++e) acc[e] = 0.f;
  for (int d0 = lane * 4; d0 < D_; d0 += 256) {
    float4 xv = *(const float4*)(xr + d0);
    ushort4 o;
    o.x = f2bf(xv.x); o.y = f2bf(xv.y); o.z = f2bf(xv.z); o.w = f2bf(xv.w);
    *(ushort4*)(xbr + d0) = o;
    const float* wr = Wg + (size_t)d0 * E_;
#pragma unroll
    for (int e = 0; e < E_; ++e)
      acc[e] += xv.x * wr[e] + xv.y * wr[E_ + e] + xv.z * wr[2 * E_ + e] +
                xv.w * wr[3 * E_ + e];
  }
#pragma unroll
  for (int off = 32; off > 0; off >>= 1) {
#pragma unroll
    for (int e = 0; e < E_; ++e) acc[e] += __shfl_down(acc[e], off, 64);
  }
  if (lane == 0) {
#pragma unroll
    for (int e = 0; e < E_; ++e)
      logitsT[((size_t)b * E_ + e) * N_ + n] = acc[e] + bg[e];
  }
}

// ---------------------------------------------------------------------------
// Exact top-K per (b,e): radix-256 select (4 passes of 8-bit digits) with
// candidate compaction. Replaces the 32-pass binary select (95.6us, 1.4%
// occupancy, latency-bound: 131K element-visits + ~96 barriers on a 32-block
// launch). Now ~12K visits + ~20 barriers. Ties lowest-index-first preserved:
// after pass 4 the surviving candidate list IS the tie set; rank by index.
// ---------------------------------------------------------------------------
__global__ __launch_bounds__(1024) void topk_kernel(const float* __restrict__ logitsT,
                                                    int* __restrict__ I,
                                                    float* __restrict__ G) {
  __shared__ unsigned keys[N_];       // 16 KB
  __shared__ unsigned hist[256];      // 1 KB
  __shared__ int candA[N_];           // 16 KB (worst-case all-ties)
  __shared__ int candB[N_];           // 16 KB
  __shared__ unsigned s_cnt;
  __shared__ unsigned s_prefix;
  __shared__ int s_rem;

  int be = blockIdx.x;
  const float* lg = logitsT + (size_t)be * N_;
  int tid = threadIdx.x;

  // Build monotonic keys.
  for (int n = tid; n < N_; n += 1024) {
    unsigned u = __float_as_uint(lg[n]);
    keys[n] = (u & 0x80000000u) ? ~u : (u | 0x80000000u);
  }
  if (tid < 256) hist[tid] = 0;
  if (tid == 0) s_cnt = 0;
  __syncthreads();

  // Pass 0: histogram top byte over all N.
  for (int n = tid; n < N_; n += 1024) atomicAdd(&hist[keys[n] >> 24], 1u);
  __syncthreads();
  if (tid == 0) {
    int r = K_;
    int d = 255;
    for (; d > 0; --d) {
      int c = (int)hist[d];
      if (c >= r) break;
      r -= c;
    }
    s_prefix = (unsigned)d << 24;
    s_rem = r;
  }
  __syncthreads();
  // Compact candidates whose top byte == threshold digit.
  {
    unsigned pfx = s_prefix;
    for (int n = tid; n < N_; n += 1024)
      if ((keys[n] & 0xFF000000u) == pfx) candA[atomicAdd(&s_cnt, 1u)] = n;
  }
  __syncthreads();
  int nc = (int)s_cnt;

  int* cur = candA;
  int* nxt = candB;
#pragma unroll
  for (int pass = 1; pass < 4; ++pass) {
    int shift = 24 - 8 * pass;
    __syncthreads();  // guard: everyone has read s_cnt into nc
    if (tid < 256) hist[tid] = 0;
    if (tid == 0) s_cnt = 0;
    __syncthreads();
    for (int i = tid; i < nc; i += 1024)
      atomicAdd(&hist[(keys[cur[i]] >> shift) & 255u], 1u);
    __syncthreads();
    if (tid == 0) {
      int r = s_rem;
      int d = 255;
      for (; d > 0; --d) {
        int c = (int)hist[d];
        if (c >= r) break;
        r -= c;
      }
      s_prefix |= (unsigned)d << shift;
      s_rem = r;
    }
    __syncthreads();
    {
      unsigned want = s_prefix;
      unsigned msk = 0xFFFFFFFFu << shift;
      for (int i = tid; i < nc; i += 1024) {
        int n = cur[i];
        if ((keys[n] & msk) == want) nxt[atomicAdd(&s_cnt, 1u)] = n;
      }
    }
    __syncthreads();
    nc = (int)s_cnt;
    int* t = cur; cur = nxt; nxt = t;
  }

  unsigned kth = s_prefix;  // exact 32-bit key of the K-th largest
  int rem = s_rem;          // how many ties to take
  int nties = nc;           // cur[0..nties) == tie set
  __syncthreads();          // guard before counter reuse
  if (tid == 0) s_cnt = 0;
  __syncthreads();

  int* Ibe = I + (size_t)be * K_;
  float* Gbe = G + (size_t)be * K_;
  // Strictly-greater elements: K_-rem of them, arbitrary order (combine is a sum).
  for (int n = tid; n < N_; n += 1024) {
    unsigned k = keys[n];
    if (k > kth) {
      unsigned p = atomicAdd(&s_cnt, 1u);
      unsigned u = (k & 0x80000000u) ? (k ^ 0x80000000u) : ~k;
      Ibe[p] = n;
      Gbe[p] = __uint_as_float(u);
    }
  }
  // Ties: take the `rem` lowest indices (jax top_k semantics), parallel rank.
  int base = K_ - rem;
  unsigned uk = (kth & 0x80000000u) ? (kth ^ 0x80000000u) : ~kth;
  float tieval = __uint_as_float(uk);
  for (int i = tid; i < nties; i += 1024) {
    int n = cur[i];
    int rank = 0;
    for (int j = 0; j < nties; ++j) rank += (cur[j] < n) ? 1 : 0;
    if (rank < rem) {
      Ibe[base + rank] = n;
      Gbe[base + rank] = tieval;
    }
  }
}

// ---------------------------------------------------------------------------
// Pre-passes: Wd -> WdT[e][r][d] bf16; Wu -> WuT[e][d][r] bf16.
// (x -> bf16 is fused into gate_kernel.)
// ---------------------------------------------------------------------------
__global__ __launch_bounds__(256) void cvt_wd_kernel(const float* __restrict__ Wd,
                                                     unsigned short* __restrict__ WdT) {
  int t = blockIdx.x * 256 + threadIdx.x;      // [e][r][d]
  int d = t & (D_ - 1);
  int r = (t >> 11) & (R_ - 1);
  int e = t >> 18;
  WdT[t] = f2bf(Wd[((size_t)e * D_ + d) * R_ + r]);
}

__global__ __launch_bounds__(256) void cvt_wu_kernel(const float* __restrict__ Wu,
                                                     unsigned short* __restrict__ WuT) {
  int t = blockIdx.x * 256 + threadIdx.x;      // [e][d][r]
  int r = t & (R_ - 1);
  int d = (t >> 7) & (D_ - 1);
  int e = t >> 18;
  WuT[t] = f2bf(Wu[((size_t)e * R_ + r) * D_ + d]);
}

__global__ __launch_bounds__(256) void init_out_kernel(const float4* __restrict__ res,
                                                       float4* __restrict__ out, int n4) {
  int i = blockIdx.x * blockDim.x + threadIdx.x;
  if (i < n4) out[i] = res[i];
}

// ---------------------------------------------------------------------------
// Down: per (b,e) gathered [1024 x 2048] @ WdT^T -> h[1024 x 128], relu, bf16.
// Block: 64x128 tile, BK=64, 4 waves of 32x64. MFMA 16x16x32 bf16.
// LDS stride 72 elems (144 B): 16B-aligned, 2-way bank alias (free).
// ---------------------------------------------------------------------------
__global__ __launch_bounds__(256) void down_mfma(const unsigned short* __restrict__ xbf,
                                                 const unsigned short* __restrict__ WdT,
                                                 const float* __restrict__ bd,
                                                 const int* __restrict__ I,
                                                 unsigned short* __restrict__ h) {
  __shared__ unsigned short As[64 * 72] __attribute__((aligned(16)));
  __shared__ unsigned short Bs[128 * 72] __attribute__((aligned(16)));
  __shared__ int s_tok[64];
  int be = blockIdx.x;
  int m0 = blockIdx.y * 64;
  int b = be >> 3, e = be & 7;
  int tid = threadIdx.x;
  if (tid < 64) s_tok[tid] = I[be * K_ + m0 + tid];
  __syncthreads();
  int lane = tid & 63, wave = tid >> 6;
  int l15 = lane & 15, quad = lane >> 4;
  int wrow = (wave >> 1) * 32, wcol = (wave & 1) * 64;

  const unsigned short* srcA[2];
  int dstA[2];
#pragma unroll
  for (int i = 0; i < 2; ++i) {
    int g = tid + 256 * i;
    int row = g >> 3, part = g & 7;
    srcA[i] = xbf + ((size_t)(b * N_ + s_tok[row])) * D_ + part * 8;
    dstA[i] = row * 72 + part * 8;
  }
  const unsigned short* Wde = WdT + (size_t)e * R_ * D_;
  const unsigned short* srcB[4];
  int dstB[4];
#pragma unroll
  for (int i = 0; i < 4; ++i) {
    int g = tid + 256 * i;
    int row = g >> 3, part = g & 7;
    srcB[i] = Wde + (size_t)row * D_ + part * 8;
    dstB[i] = row * 72 + part * 8;
  }

  f32x4 zv = {0.f, 0.f, 0.f, 0.f};
  f32x4 acc[2][4];
#pragma unroll
  for (int mi = 0; mi < 2; ++mi)
#pragma unroll
    for (int ni = 0; ni < 4; ++ni) acc[mi][ni] = zv;

  for (int d0 = 0; d0 < D_; d0 += 64) {
#pragma unroll
    for (int i = 0; i < 2; ++i)
      *(uint4*)&As[dstA[i]] = *(const uint4*)(srcA[i] + d0);
#pragma unroll
    for (int i = 0; i < 4; ++i)
      *(uint4*)&Bs[dstB[i]] = *(const uint4*)(srcB[i] + d0);
    __syncthreads();
#pragma unroll
    for (int ks = 0; ks < 64; ks += 32) {
      bf16x8 a[2], bb[4];
#pragma unroll
      for (int mi = 0; mi < 2; ++mi)
        a[mi] = *(const bf16x8*)&As[(wrow + mi * 16 + l15) * 72 + ks + quad * 8];
#pragma unroll
      for (int ni = 0; ni < 4; ++ni)
        bb[ni] = *(const bf16x8*)&Bs[(wcol + ni * 16 + l15) * 72 + ks + quad * 8];
#pragma unroll
      for (int mi = 0; mi < 2; ++mi)
#pragma unroll
        for (int ni = 0; ni < 4; ++ni)
          acc[mi][ni] = __builtin_amdgcn_mfma_f32_16x16x32_bf16(a[mi], bb[ni], acc[mi][ni], 0, 0, 0);
    }
    __syncthreads();
  }
#pragma unroll
  for (int mi = 0; mi < 2; ++mi) {
#pragma unroll
    for (int ni = 0; ni < 4; ++ni) {
      int col = wcol + ni * 16 + l15;
      float bias = bd[e * R_ + col];
#pragma unroll
      for (int r = 0; r < 4; ++r) {
        int mrow = m0 + wrow + mi * 16 + quad * 4 + r;
        float v = acc[mi][ni][r] + bias;
        h[((size_t)be * K_ + mrow) * R_ + col] = f2bf(v > 0.f ? v : 0.f);
      }
    }
  }
}

// ---------------------------------------------------------------------------
// Up (one expert per launch => top-K tokens distinct => atomic-free RMW):
// h[128 x 128] @ WuT^T chunk -> out[b,tok,n0+c] += g*(acc + bu + x).
// Block: 128x128, K=R=128 single stage, 4 waves of 64x64.
// LDS stride 136 elems (272 B): 16B-aligned, 2-way bank alias.
// ---------------------------------------------------------------------------
__global__ __launch_bounds__(256) void up_mfma(const float* __restrict__ x,
                                               const unsigned short* __restrict__ WuT,
                                               const float* __restrict__ bu,
                                               const int* __restrict__ I,
                                               const float* __restrict__ G,
                                               const unsigned short* __restrict__ h,
                                               float* __restrict__ out, int e) {
  __shared__ unsigned short As[128 * 136] __attribute__((aligned(16)));
  __shared__ unsigned short Bs[128 * 136] __attribute__((aligned(16)));
  __shared__ int s_tok[128];
  __shared__ float s_g[128];
  int ntile = blockIdx.x;   // 16
  int mtile = blockIdx.y;   // 8
  int b = blockIdx.z;       // 4
  int be = b * E_ + e;
  int m0 = mtile * 128, n0 = ntile * 128;
  int tid = threadIdx.x;
  if (tid < 128) {
    s_tok[tid] = I[be * K_ + m0 + tid];
    s_g[tid] = G[be * K_ + m0 + tid];
  }
  const unsigned short* hbe = h + ((size_t)be * K_ + m0) * R_;
  const unsigned short* Wue = WuT + ((size_t)e * D_ + n0) * R_;
#pragma unroll
  for (int i = 0; i < 8; ++i) {
    int g = tid + 256 * i;
    int row = g >> 4, part = g & 15;
    *(uint4*)&As[row * 136 + part * 8] = *(const uint4*)(hbe + (size_t)row * R_ + part * 8);
  }
#pragma unroll
  for (int i = 0; i < 8; ++i) {
    int g = tid + 256 * i;
    int row = g >> 4, part = g & 15;
    *(uint4*)&Bs[row * 136 + part * 8] = *(const uint4*)(Wue + (size_t)row * R_ + part * 8);
  }
  __syncthreads();

  int lane = tid & 63, wave = tid >> 6;
  int l15 = lane & 15, quad = lane >> 4;
  int wrow = (wave >> 1) * 64, wcol = (wave & 1) * 64;
  f32x4 zv = {0.f, 0.f, 0.f, 0.f};
  f32x4 acc[4][4];
#pragma unroll
  for (int mi = 0; mi < 4; ++mi)
#pragma unroll
    for (int ni = 0; ni < 4; ++ni) acc[mi][ni] = zv;

#pragma unroll
  for (int ks = 0; ks < 128; ks += 32) {
    bf16x8 a[4], bb[4];
#pragma unroll
    for (int mi = 0; mi < 4; ++mi)
      a[mi] = *(const bf16x8*)&As[(wrow + mi * 16 + l15) * 136 + ks + quad * 8];
#pragma unroll
    for (int ni = 0; ni < 4; ++ni)
      bb[ni] = *(const bf16x8*)&Bs[(wcol + ni * 16 + l15) * 136 + ks + quad * 8];
#pragma unroll
    for (int mi = 0; mi < 4; ++mi)
#pragma unroll
      for (int ni = 0; ni < 4; ++ni)
        acc[mi][ni] = __builtin_amdgcn_mfma_f32_16x16x32_bf16(a[mi], bb[ni], acc[mi][ni], 0, 0, 0);
  }

#pragma unroll
  for (int mi = 0; mi < 4; ++mi) {
#pragma unroll
    for (int r = 0; r < 4; ++r) {
      int row = wrow + mi * 16 + quad * 4 + r;
      int tok = s_tok[row];
      float g = s_g[row];
      const float* xr = x + ((size_t)(b * N_ + tok)) * D_ + n0;
      float* outr = out + ((size_t)(b * N_ + tok)) * D_ + n0;
#pragma unroll
      for (int ni = 0; ni < 4; ++ni) {
        int col = wcol + ni * 16 + l15;
        float v = g * (acc[mi][ni][r] + bu[e * D_ + n0 + col] + xr[col]);
        outr[col] += v;  // race-free: tokens distinct within (b,e); experts serialized by launch
      }
    }
  }
}

// ---------------------------------------------------------------------------
extern "C" void kernel_launch(void* const* d_in, const int* in_sizes, int n_in,
                              void* d_out, int out_size, void* d_ws, size_t ws_size,
                              hipStream_t stream) {
  const float* x        = (const float*)d_in[0];
  const float* residual = (const float*)d_in[1];
  const float* Wg       = (const float*)d_in[2];
  const float* bg       = (const float*)d_in[3];
  const float* Wd       = (const float*)d_in[4];
  const float* bd       = (const float*)d_in[5];
  const float* Wu       = (const float*)d_in[6];
  const float* bu       = (const float*)d_in[7];
  float* out = (float*)d_out;

  // ws layout (all region sizes 256B-multiples):
  // logitsT f32[B*E*N] | I i32[B*E*K] | G f32[B*E*K] | xbf bf16[B*N*D]
  // | WdT bf16[E*R*D] | WuT bf16[E*D*R] | h bf16[B*E*K*R]     (~85 MB)
  char* p = (char*)d_ws;
  float* logitsT = (float*)p;            p += (size_t)B_ * E_ * N_ * 4;
  int* Ibuf = (int*)p;                   p += (size_t)B_ * E_ * K_ * 4;
  float* Gbuf = (float*)p;               p += (size_t)B_ * E_ * K_ * 4;
  unsigned short* xbf = (unsigned short*)p;  p += (size_t)B_ * N_ * D_ * 2;
  unsigned short* WdT = (unsigned short*)p;  p += (size_t)E_ * R_ * D_ * 2;
  unsigned short* WuT = (unsigned short*)p;  p += (size_t)E_ * D_ * R_ * 2;
  unsigned short* hbuf = (unsigned short*)p;

  gate_kernel<<<B_ * N_ / 4, 256, 0, stream>>>(x, Wg, bg, logitsT, xbf);
  topk_kernel<<<B_ * E_, 1024, 0, stream>>>(logitsT, Ibuf, Gbuf);
  cvt_wd_kernel<<<E_ * D_ * R_ / 256, 256, 0, stream>>>(Wd, WdT);
  cvt_wu_kernel<<<E_ * D_ * R_ / 256, 256, 0, stream>>>(Wu, WuT);
  init_out_kernel<<<B_ * N_ * D_ / 4 / 256, 256, 0, stream>>>(
      (const float4*)residual, (float4*)out, B_ * N_ * D_ / 4);
  down_mfma<<<dim3(B_ * E_, K_ / 64), 256, 0, stream>>>(xbf, WdT, bd, Ibuf, hbuf);
  for (int e = 0; e < E_; ++e)
    up_mfma<<<dim3(D_ / 128, K_ / 128, B_), 256, 0, stream>>>(
        x, WuT, bu, Ibuf, Gbuf, hbuf, out, e);
}

// Round 2
// 633.721 us; speedup vs baseline: 1.1513x; 1.1260x over previous
//
#include <hip/hip_runtime.h>

#define B_ 4
#define N_ 4096
#define D_ 2048
#define E_ 8
#define R_ 128
#define K_ 1024

typedef __attribute__((ext_vector_type(8))) short bf16x8;
typedef __attribute__((ext_vector_type(4))) float f32x4;

__device__ inline unsigned short f2bf(float f) {
  unsigned u = __float_as_uint(f);
  unsigned r = (u + 0x7FFFu + ((u >> 16) & 1u)) >> 16;  // RNE
  return (unsigned short)r;
}

// ---------------------------------------------------------------------------
// Gate logits (fp32 — top-k boundary gaps ~1e-3 require fp32 precision) fused
// with x->bf16 conversion. Round-1 fix: the per-lane scalar gather of Wg
// (256 instrs/wave x ~32 cachelines each) was TA-pipe bound (152us, 11% HBM,
// 10% VALU). Now Wg is staged TRANSPOSED in LDS (sWg[e][d], 64KB) once per
// 16-wave block; inner reads are ds_read_b128 with the wave covering a
// contiguous 1KB (bank-perfect). Arithmetic order identical -> same logits.
// ---------------------------------------------------------------------------
__global__ __launch_bounds__(1024) void gate_kernel(const float* __restrict__ x,
                                                    const float* __restrict__ Wg,
                                                    const float* __restrict__ bg,
                                                    float* __restrict__ logitsT,
                                                    unsigned short* __restrict__ xbf) {
  __shared__ float sWg[E_ * D_];  // 64 KB, [e][d]
  int tid = threadIdx.x;
  // Stage Wg transposed: coalesced float4 reads of Wg[d][e] (f = d*8+e).
  for (int f = tid * 4; f < D_ * E_; f += 1024 * 4) {
    float4 w = *(const float4*)(Wg + f);
    int d = f >> 3, e0 = f & 7;  // float4 spans e0..e0+3 (e0 in {0,4})
    sWg[(e0 + 0) * D_ + d] = w.x;
    sWg[(e0 + 1) * D_ + d] = w.y;
    sWg[(e0 + 2) * D_ + d] = w.z;
    sWg[(e0 + 3) * D_ + d] = w.w;
  }
  __syncthreads();

  int wave = tid >> 6;
  int lane = tid & 63;
  int token = blockIdx.x * 16 + wave;
  int b = token >> 12;          // token / N_
  int n = token & (N_ - 1);     // token % N_
  const float* xr = x + (size_t)token * D_;
  unsigned short* xbr = xbf + (size_t)token * D_;
  float acc[E_];
#pragma unroll
  for (int e = 0; e < E_; ++e) acc[e] = 0.f;
  for (int d0 = lane * 4; d0 < D_; d0 += 256) {
    float4 xv = *(const float4*)(xr + d0);
    ushort4 o;
    o.x = f2bf(xv.x); o.y = f2bf(xv.y); o.z = f2bf(xv.z); o.w = f2bf(xv.w);
    *(ushort4*)(xbr + d0) = o;
#pragma unroll
    for (int e = 0; e < E_; ++e) {
      float4 w = *(const float4*)(&sWg[e * D_ + d0]);
      acc[e] += xv.x * w.x + xv.y * w.y + xv.z * w.z + xv.w * w.w;
    }
  }
#pragma unroll
  for (int off = 32; off > 0; off >>= 1) {
#pragma unroll
    for (int e = 0; e < E_; ++e) acc[e] += __shfl_down(acc[e], off, 64);
  }
  if (lane == 0) {
#pragma unroll
    for (int e = 0; e < E_; ++e)
      logitsT[((size_t)b * E_ + e) * N_ + n] = acc[e] + bg[e];
  }
}

// ---------------------------------------------------------------------------
// Exact top-K per (b,e): radix-256 select (4 passes of 8-bit digits) with
// candidate compaction. Ties lowest-index-first preserved.
// ---------------------------------------------------------------------------
__global__ __launch_bounds__(1024) void topk_kernel(const float* __restrict__ logitsT,
                                                    int* __restrict__ I,
                                                    float* __restrict__ G) {
  __shared__ unsigned keys[N_];       // 16 KB
  __shared__ unsigned hist[256];      // 1 KB
  __shared__ int candA[N_];           // 16 KB (worst-case all-ties)
  __shared__ int candB[N_];           // 16 KB
  __shared__ unsigned s_cnt;
  __shared__ unsigned s_prefix;
  __shared__ int s_rem;

  int be = blockIdx.x;
  const float* lg = logitsT + (size_t)be * N_;
  int tid = threadIdx.x;

  // Build monotonic keys.
  for (int n = tid; n < N_; n += 1024) {
    unsigned u = __float_as_uint(lg[n]);
    keys[n] = (u & 0x80000000u) ? ~u : (u | 0x80000000u);
  }
  if (tid < 256) hist[tid] = 0;
  if (tid == 0) s_cnt = 0;
  __syncthreads();

  // Pass 0: histogram top byte over all N.
  for (int n = tid; n < N_; n += 1024) atomicAdd(&hist[keys[n] >> 24], 1u);
  __syncthreads();
  if (tid == 0) {
    int r = K_;
    int d = 255;
    for (; d > 0; --d) {
      int c = (int)hist[d];
      if (c >= r) break;
      r -= c;
    }
    s_prefix = (unsigned)d << 24;
    s_rem = r;
  }
  __syncthreads();
  // Compact candidates whose top byte == threshold digit.
  {
    unsigned pfx = s_prefix;
    for (int n = tid; n < N_; n += 1024)
      if ((keys[n] & 0xFF000000u) == pfx) candA[atomicAdd(&s_cnt, 1u)] = n;
  }
  __syncthreads();
  int nc = (int)s_cnt;

  int* cur = candA;
  int* nxt = candB;
#pragma unroll
  for (int pass = 1; pass < 4; ++pass) {
    int shift = 24 - 8 * pass;
    __syncthreads();  // guard: everyone has read s_cnt into nc
    if (tid < 256) hist[tid] = 0;
    if (tid == 0) s_cnt = 0;
    __syncthreads();
    for (int i = tid; i < nc; i += 1024)
      atomicAdd(&hist[(keys[cur[i]] >> shift) & 255u], 1u);
    __syncthreads();
    if (tid == 0) {
      int r = s_rem;
      int d = 255;
      for (; d > 0; --d) {
        int c = (int)hist[d];
        if (c >= r) break;
        r -= c;
      }
      s_prefix |= (unsigned)d << shift;
      s_rem = r;
    }
    __syncthreads();
    {
      unsigned want = s_prefix;
      unsigned msk = 0xFFFFFFFFu << shift;
      for (int i = tid; i < nc; i += 1024) {
        int n = cur[i];
        if ((keys[n] & msk) == want) nxt[atomicAdd(&s_cnt, 1u)] = n;
      }
    }
    __syncthreads();
    nc = (int)s_cnt;
    int* t = cur; cur = nxt; nxt = t;
  }

  unsigned kth = s_prefix;  // exact 32-bit key of the K-th largest
  int rem = s_rem;          // how many ties to take
  int nties = nc;           // cur[0..nties) == tie set
  __syncthreads();          // guard before counter reuse
  if (tid == 0) s_cnt = 0;
  __syncthreads();

  int* Ibe = I + (size_t)be * K_;
  float* Gbe = G + (size_t)be * K_;
  // Strictly-greater elements: K_-rem of them, arbitrary order (combine is a sum).
  for (int n = tid; n < N_; n += 1024) {
    unsigned k = keys[n];
    if (k > kth) {
      unsigned p = atomicAdd(&s_cnt, 1u);
      unsigned u = (k & 0x80000000u) ? (k ^ 0x80000000u) : ~k;
      Ibe[p] = n;
      Gbe[p] = __uint_as_float(u);
    }
  }
  // Ties: take the `rem` lowest indices (jax top_k semantics), parallel rank.
  int base = K_ - rem;
  unsigned uk = (kth & 0x80000000u) ? (kth ^ 0x80000000u) : ~kth;
  float tieval = __uint_as_float(uk);
  for (int i = tid; i < nties; i += 1024) {
    int n = cur[i];
    int rank = 0;
    for (int j = 0; j < nties; ++j) rank += (cur[j] < n) ? 1 : 0;
    if (rank < rem) {
      Ibe[base + rank] = n;
      Gbe[base + rank] = tieval;
    }
  }
}

// ---------------------------------------------------------------------------
// Pre-passes: Wd -> WdT[e][r][d] bf16; Wu -> WuT[e][d][r] bf16.
// (x -> bf16 is fused into gate_kernel.)
// ---------------------------------------------------------------------------
__global__ __launch_bounds__(256) void cvt_wd_kernel(const float* __restrict__ Wd,
                                                     unsigned short* __restrict__ WdT) {
  int t = blockIdx.x * 256 + threadIdx.x;      // [e][r][d]
  int d = t & (D_ - 1);
  int r = (t >> 11) & (R_ - 1);
  int e = t >> 18;
  WdT[t] = f2bf(Wd[((size_t)e * D_ + d) * R_ + r]);
}

__global__ __launch_bounds__(256) void cvt_wu_kernel(const float* __restrict__ Wu,
                                                     unsigned short* __restrict__ WuT) {
  int t = blockIdx.x * 256 + threadIdx.x;      // [e][d][r]
  int r = t & (R_ - 1);
  int d = (t >> 7) & (D_ - 1);
  int e = t >> 18;
  WuT[t] = f2bf(Wu[((size_t)e * R_ + r) * D_ + d]);
}

__global__ __launch_bounds__(256) void init_out_kernel(const float4* __restrict__ res,
                                                       float4* __restrict__ out, int n4) {
  int i = blockIdx.x * blockDim.x + threadIdx.x;
  if (i < n4) out[i] = res[i];
}

// ---------------------------------------------------------------------------
// Down: per (b,e) gathered [1024 x 2048] @ WdT^T -> h[1024 x 128], relu, bf16.
// Block: 64x128 tile, BK=64, 4 waves of 32x64. MFMA 16x16x32 bf16.
// LDS stride 72 elems (144 B): 16B-aligned, 2-way bank alias (free).
// ---------------------------------------------------------------------------
__global__ __launch_bounds__(256) void down_mfma(const unsigned short* __restrict__ xbf,
                                                 const unsigned short* __restrict__ WdT,
                                                 const float* __restrict__ bd,
                                                 const int* __restrict__ I,
                                                 unsigned short* __restrict__ h) {
  __shared__ unsigned short As[64 * 72] __attribute__((aligned(16)));
  __shared__ unsigned short Bs[128 * 72] __attribute__((aligned(16)));
  __shared__ int s_tok[64];
  int be = blockIdx.x;
  int m0 = blockIdx.y * 64;
  int b = be >> 3, e = be & 7;
  int tid = threadIdx.x;
  if (tid < 64) s_tok[tid] = I[be * K_ + m0 + tid];
  __syncthreads();
  int lane = tid & 63, wave = tid >> 6;
  int l15 = lane & 15, quad = lane >> 4;
  int wrow = (wave >> 1) * 32, wcol = (wave & 1) * 64;

  const unsigned short* srcA[2];
  int dstA[2];
#pragma unroll
  for (int i = 0; i < 2; ++i) {
    int g = tid + 256 * i;
    int row = g >> 3, part = g & 7;
    srcA[i] = xbf + ((size_t)(b * N_ + s_tok[row])) * D_ + part * 8;
    dstA[i] = row * 72 + part * 8;
  }
  const unsigned short* Wde = WdT + (size_t)e * R_ * D_;
  const unsigned short* srcB[4];
  int dstB[4];
#pragma unroll
  for (int i = 0; i < 4; ++i) {
    int g = tid + 256 * i;
    int row = g >> 3, part = g & 7;
    srcB[i] = Wde + (size_t)row * D_ + part * 8;
    dstB[i] = row * 72 + part * 8;
  }

  f32x4 zv = {0.f, 0.f, 0.f, 0.f};
  f32x4 acc[2][4];
#pragma unroll
  for (int mi = 0; mi < 2; ++mi)
#pragma unroll
    for (int ni = 0; ni < 4; ++ni) acc[mi][ni] = zv;

  for (int d0 = 0; d0 < D_; d0 += 64) {
#pragma unroll
    for (int i = 0; i < 2; ++i)
      *(uint4*)&As[dstA[i]] = *(const uint4*)(srcA[i] + d0);
#pragma unroll
    for (int i = 0; i < 4; ++i)
      *(uint4*)&Bs[dstB[i]] = *(const uint4*)(srcB[i] + d0);
    __syncthreads();
#pragma unroll
    for (int ks = 0; ks < 64; ks += 32) {
      bf16x8 a[2], bb[4];
#pragma unroll
      for (int mi = 0; mi < 2; ++mi)
        a[mi] = *(const bf16x8*)&As[(wrow + mi * 16 + l15) * 72 + ks + quad * 8];
#pragma unroll
      for (int ni = 0; ni < 4; ++ni)
        bb[ni] = *(const bf16x8*)&Bs[(wcol + ni * 16 + l15) * 72 + ks + quad * 8];
#pragma unroll
      for (int mi = 0; mi < 2; ++mi)
#pragma unroll
        for (int ni = 0; ni < 4; ++ni)
          acc[mi][ni] = __builtin_amdgcn_mfma_f32_16x16x32_bf16(a[mi], bb[ni], acc[mi][ni], 0, 0, 0);
    }
    __syncthreads();
  }
#pragma unroll
  for (int mi = 0; mi < 2; ++mi) {
#pragma unroll
    for (int ni = 0; ni < 4; ++ni) {
      int col = wcol + ni * 16 + l15;
      float bias = bd[e * R_ + col];
#pragma unroll
      for (int r = 0; r < 4; ++r) {
        int mrow = m0 + wrow + mi * 16 + quad * 4 + r;
        float v = acc[mi][ni][r] + bias;
        h[((size_t)be * K_ + mrow) * R_ + col] = f2bf(v > 0.f ? v : 0.f);
      }
    }
  }
}

// ---------------------------------------------------------------------------
// Up (one expert per launch => top-K tokens distinct => atomic-free RMW):
// h[128 x 128] @ WuT^T chunk -> out[b,tok,n0+c] += g*(acc + bu + x).
// Block: 128x128, K=R=128 single stage, 4 waves of 64x64.
// LDS stride 136 elems (272 B): 16B-aligned, 2-way bank alias.
// ---------------------------------------------------------------------------
__global__ __launch_bounds__(256) void up_mfma(const float* __restrict__ x,
                                               const unsigned short* __restrict__ WuT,
                                               const float* __restrict__ bu,
                                               const int* __restrict__ I,
                                               const float* __restrict__ G,
                                               const unsigned short* __restrict__ h,
                                               float* __restrict__ out, int e) {
  __shared__ unsigned short As[128 * 136] __attribute__((aligned(16)));
  __shared__ unsigned short Bs[128 * 136] __attribute__((aligned(16)));
  __shared__ int s_tok[128];
  __shared__ float s_g[128];
  int ntile = blockIdx.x;   // 16
  int mtile = blockIdx.y;   // 8
  int b = blockIdx.z;       // 4
  int be = b * E_ + e;
  int m0 = mtile * 128, n0 = ntile * 128;
  int tid = threadIdx.x;
  if (tid < 128) {
    s_tok[tid] = I[be * K_ + m0 + tid];
    s_g[tid] = G[be * K_ + m0 + tid];
  }
  const unsigned short* hbe = h + ((size_t)be * K_ + m0) * R_;
  const unsigned short* Wue = WuT + ((size_t)e * D_ + n0) * R_;
#pragma unroll
  for (int i = 0; i < 8; ++i) {
    int g = tid + 256 * i;
    int row = g >> 4, part = g & 15;
    *(uint4*)&As[row * 136 + part * 8] = *(const uint4*)(hbe + (size_t)row * R_ + part * 8);
  }
#pragma unroll
  for (int i = 0; i < 8; ++i) {
    int g = tid + 256 * i;
    int row = g >> 4, part = g & 15;
    *(uint4*)&Bs[row * 136 + part * 8] = *(const uint4*)(Wue + (size_t)row * R_ + part * 8);
  }
  __syncthreads();

  int lane = tid & 63, wave = tid >> 6;
  int l15 = lane & 15, quad = lane >> 4;
  int wrow = (wave >> 1) * 64, wcol = (wave & 1) * 64;
  f32x4 zv = {0.f, 0.f, 0.f, 0.f};
  f32x4 acc[4][4];
#pragma unroll
  for (int mi = 0; mi < 4; ++mi)
#pragma unroll
    for (int ni = 0; ni < 4; ++ni) acc[mi][ni] = zv;

#pragma unroll
  for (int ks = 0; ks < 128; ks += 32) {
    bf16x8 a[4], bb[4];
#pragma unroll
    for (int mi = 0; mi < 4; ++mi)
      a[mi] = *(const bf16x8*)&As[(wrow + mi * 16 + l15) * 136 + ks + quad * 8];
#pragma unroll
    for (int ni = 0; ni < 4; ++ni)
      bb[ni] = *(const bf16x8*)&Bs[(wcol + ni * 16 + l15) * 136 + ks + quad * 8];
#pragma unroll
    for (int mi = 0; mi < 4; ++mi)
#pragma unroll
      for (int ni = 0; ni < 4; ++ni)
        acc[mi][ni] = __builtin_amdgcn_mfma_f32_16x16x32_bf16(a[mi], bb[ni], acc[mi][ni], 0, 0, 0);
  }

#pragma unroll
  for (int mi = 0; mi < 4; ++mi) {
#pragma unroll
    for (int r = 0; r < 4; ++r) {
      int row = wrow + mi * 16 + quad * 4 + r;
      int tok = s_tok[row];
      float g = s_g[row];
      const float* xr = x + ((size_t)(b * N_ + tok)) * D_ + n0;
      float* outr = out + ((size_t)(b * N_ + tok)) * D_ + n0;
#pragma unroll
      for (int ni = 0; ni < 4; ++ni) {
        int col = wcol + ni * 16 + l15;
        float v = g * (acc[mi][ni][r] + bu[e * D_ + n0 + col] + xr[col]);
        outr[col] += v;  // race-free: tokens distinct within (b,e); experts serialized by launch
      }
    }
  }
}

// ---------------------------------------------------------------------------
extern "C" void kernel_launch(void* const* d_in, const int* in_sizes, int n_in,
                              void* d_out, int out_size, void* d_ws, size_t ws_size,
                              hipStream_t stream) {
  const float* x        = (const float*)d_in[0];
  const float* residual = (const float*)d_in[1];
  const float* Wg       = (const float*)d_in[2];
  const float* bg       = (const float*)d_in[3];
  const float* Wd       = (const float*)d_in[4];
  const float* bd       = (const float*)d_in[5];
  const float* Wu       = (const float*)d_in[6];
  const float* bu       = (const float*)d_in[7];
  float* out = (float*)d_out;

  // ws layout (all region sizes 256B-multiples):
  // logitsT f32[B*E*N] | I i32[B*E*K] | G f32[B*E*K] | xbf bf16[B*N*D]
  // | WdT bf16[E*R*D] | WuT bf16[E*D*R] | h bf16[B*E*K*R]     (~85 MB)
  char* p = (char*)d_ws;
  float* logitsT = (float*)p;            p += (size_t)B_ * E_ * N_ * 4;
  int* Ibuf = (int*)p;                   p += (size_t)B_ * E_ * K_ * 4;
  float* Gbuf = (float*)p;               p += (size_t)B_ * E_ * K_ * 4;
  unsigned short* xbf = (unsigned short*)p;  p += (size_t)B_ * N_ * D_ * 2;
  unsigned short* WdT = (unsigned short*)p;  p += (size_t)E_ * R_ * D_ * 2;
  unsigned short* WuT = (unsigned short*)p;  p += (size_t)E_ * D_ * R_ * 2;
  unsigned short* hbuf = (unsigned short*)p;

  gate_kernel<<<B_ * N_ / 16, 1024, 0, stream>>>(x, Wg, bg, logitsT, xbf);
  topk_kernel<<<B_ * E_, 1024, 0, stream>>>(logitsT, Ibuf, Gbuf);
  cvt_wd_kernel<<<E_ * D_ * R_ / 256, 256, 0, stream>>>(Wd, WdT);
  cvt_wu_kernel<<<E_ * D_ * R_ / 256, 256, 0, stream>>>(Wu, WuT);
  init_out_kernel<<<B_ * N_ * D_ / 4 / 256, 256, 0, stream>>>(
      (const float4*)residual, (float4*)out, B_ * N_ * D_ / 4);
  down_mfma<<<dim3(B_ * E_, K_ / 64), 256, 0, stream>>>(xbf, WdT, bd, Ibuf, hbuf);
  for (int e = 0; e < E_; ++e)
    up_mfma<<<dim3(D_ / 128, K_ / 128, B_), 256, 0, stream>>>(
        x, WuT, bu, Ibuf, Gbuf, hbuf, out, e);
}

// Round 3
// 593.821 us; speedup vs baseline: 1.2286x; 1.0672x over previous
//
#include <hip/hip_runtime.h>

#define B_ 4
#define N_ 4096
#define D_ 2048
#define E_ 8
#define R_ 128
#define K_ 1024

typedef __attribute__((ext_vector_type(8))) short bf16x8;
typedef __attribute__((ext_vector_type(4))) float f32x4;

__device__ inline unsigned short f2bf(float f) {
  unsigned u = __float_as_uint(f);
  unsigned r = (u + 0x7FFFu + ((u >> 16) & 1u)) >> 16;  // RNE
  return (unsigned short)r;
}

// ---------------------------------------------------------------------------
// Gate logits (fp32) fused with x->bf16 conversion. Wg staged transposed in
// LDS (sWg[e][d], 64KB); inner reads are ds_read_b128, bank-perfect.
// ---------------------------------------------------------------------------
__global__ __launch_bounds__(1024) void gate_kernel(const float* __restrict__ x,
                                                    const float* __restrict__ Wg,
                                                    const float* __restrict__ bg,
                                                    float* __restrict__ logitsT,
                                                    unsigned short* __restrict__ xbf) {
  __shared__ float sWg[E_ * D_];  // 64 KB, [e][d]
  int tid = threadIdx.x;
  for (int f = tid * 4; f < D_ * E_; f += 1024 * 4) {
    float4 w = *(const float4*)(Wg + f);
    int d = f >> 3, e0 = f & 7;
    sWg[(e0 + 0) * D_ + d] = w.x;
    sWg[(e0 + 1) * D_ + d] = w.y;
    sWg[(e0 + 2) * D_ + d] = w.z;
    sWg[(e0 + 3) * D_ + d] = w.w;
  }
  __syncthreads();

  int wave = tid >> 6;
  int lane = tid & 63;
  int token = blockIdx.x * 16 + wave;
  int b = token >> 12;
  int n = token & (N_ - 1);
  const float* xr = x + (size_t)token * D_;
  unsigned short* xbr = xbf + (size_t)token * D_;
  float acc[E_];
#pragma unroll
  for (int e = 0; e < E_; ++e) acc[e] = 0.f;
  for (int d0 = lane * 4; d0 < D_; d0 += 256) {
    float4 xv = *(const float4*)(xr + d0);
    ushort4 o;
    o.x = f2bf(xv.x); o.y = f2bf(xv.y); o.z = f2bf(xv.z); o.w = f2bf(xv.w);
    *(ushort4*)(xbr + d0) = o;
#pragma unroll
    for (int e = 0; e < E_; ++e) {
      float4 w = *(const float4*)(&sWg[e * D_ + d0]);
      acc[e] += xv.x * w.x + xv.y * w.y + xv.z * w.z + xv.w * w.w;
    }
  }
#pragma unroll
  for (int off = 32; off > 0; off >>= 1) {
#pragma unroll
    for (int e = 0; e < E_; ++e) acc[e] += __shfl_down(acc[e], off, 64);
  }
  if (lane == 0) {
#pragma unroll
    for (int e = 0; e < E_; ++e)
      logitsT[((size_t)b * E_ + e) * N_ + n] = acc[e] + bg[e];
  }
}

// ---------------------------------------------------------------------------
// Exact top-K per (b,e): radix-256 select with candidate compaction.
// Ties lowest-index-first preserved.
// ---------------------------------------------------------------------------
__global__ __launch_bounds__(1024) void topk_kernel(const float* __restrict__ logitsT,
                                                    int* __restrict__ I,
                                                    float* __restrict__ G) {
  __shared__ unsigned keys[N_];
  __shared__ unsigned hist[256];
  __shared__ int candA[N_];
  __shared__ int candB[N_];
  __shared__ unsigned s_cnt;
  __shared__ unsigned s_prefix;
  __shared__ int s_rem;

  int be = blockIdx.x;
  const float* lg = logitsT + (size_t)be * N_;
  int tid = threadIdx.x;

  for (int n = tid; n < N_; n += 1024) {
    unsigned u = __float_as_uint(lg[n]);
    keys[n] = (u & 0x80000000u) ? ~u : (u | 0x80000000u);
  }
  if (tid < 256) hist[tid] = 0;
  if (tid == 0) s_cnt = 0;
  __syncthreads();

  for (int n = tid; n < N_; n += 1024) atomicAdd(&hist[keys[n] >> 24], 1u);
  __syncthreads();
  if (tid == 0) {
    int r = K_;
    int d = 255;
    for (; d > 0; --d) {
      int c = (int)hist[d];
      if (c >= r) break;
      r -= c;
    }
    s_prefix = (unsigned)d << 24;
    s_rem = r;
  }
  __syncthreads();
  {
    unsigned pfx = s_prefix;
    for (int n = tid; n < N_; n += 1024)
      if ((keys[n] & 0xFF000000u) == pfx) candA[atomicAdd(&s_cnt, 1u)] = n;
  }
  __syncthreads();
  int nc = (int)s_cnt;

  int* cur = candA;
  int* nxt = candB;
#pragma unroll
  for (int pass = 1; pass < 4; ++pass) {
    int shift = 24 - 8 * pass;
    __syncthreads();
    if (tid < 256) hist[tid] = 0;
    if (tid == 0) s_cnt = 0;
    __syncthreads();
    for (int i = tid; i < nc; i += 1024)
      atomicAdd(&hist[(keys[cur[i]] >> shift) & 255u], 1u);
    __syncthreads();
    if (tid == 0) {
      int r = s_rem;
      int d = 255;
      for (; d > 0; --d) {
        int c = (int)hist[d];
        if (c >= r) break;
        r -= c;
      }
      s_prefix |= (unsigned)d << shift;
      s_rem = r;
    }
    __syncthreads();
    {
      unsigned want = s_prefix;
      unsigned msk = 0xFFFFFFFFu << shift;
      for (int i = tid; i < nc; i += 1024) {
        int n = cur[i];
        if ((keys[n] & msk) == want) nxt[atomicAdd(&s_cnt, 1u)] = n;
      }
    }
    __syncthreads();
    nc = (int)s_cnt;
    int* t = cur; cur = nxt; nxt = t;
  }

  unsigned kth = s_prefix;
  int rem = s_rem;
  int nties = nc;
  __syncthreads();
  if (tid == 0) s_cnt = 0;
  __syncthreads();

  int* Ibe = I + (size_t)be * K_;
  float* Gbe = G + (size_t)be * K_;
  for (int n = tid; n < N_; n += 1024) {
    unsigned k = keys[n];
    if (k > kth) {
      unsigned p = atomicAdd(&s_cnt, 1u);
      unsigned u = (k & 0x80000000u) ? (k ^ 0x80000000u) : ~k;
      Ibe[p] = n;
      Gbe[p] = __uint_as_float(u);
    }
  }
  int base = K_ - rem;
  unsigned uk = (kth & 0x80000000u) ? (kth ^ 0x80000000u) : ~kth;
  float tieval = __uint_as_float(uk);
  for (int i = tid; i < nties; i += 1024) {
    int n = cur[i];
    int rank = 0;
    for (int j = 0; j < nties; ++j) rank += (cur[j] < n) ? 1 : 0;
    if (rank < rem) {
      Ibe[base + rank] = n;
      Gbe[base + rank] = tieval;
    }
  }
}

// ---------------------------------------------------------------------------
// Pre-passes: Wd -> WdT[e][r][d] bf16; Wu -> WuT[e][d][r] bf16.
// ---------------------------------------------------------------------------
__global__ __launch_bounds__(256) void cvt_wd_kernel(const float* __restrict__ Wd,
                                                     unsigned short* __restrict__ WdT) {
  int t = blockIdx.x * 256 + threadIdx.x;      // [e][r][d]
  int d = t & (D_ - 1);
  int r = (t >> 11) & (R_ - 1);
  int e = t >> 18;
  WdT[t] = f2bf(Wd[((size_t)e * D_ + d) * R_ + r]);
}

__global__ __launch_bounds__(256) void cvt_wu_kernel(const float* __restrict__ Wu,
                                                     unsigned short* __restrict__ WuT) {
  int t = blockIdx.x * 256 + threadIdx.x;      // [e][d][r]
  int r = t & (R_ - 1);
  int d = (t >> 7) & (D_ - 1);
  int e = t >> 18;
  WuT[t] = f2bf(Wu[((size_t)e * R_ + r) * D_ + d]);
}

// ---------------------------------------------------------------------------
// Inverse routing index: for each token (b,n), the list of (e,k,g) that chose
// it (max E_=8 entries). Built from topk output (32K entries, trivial cost).
// Replaces the 8 serialized expert launches' RMW race-avoidance.
// ---------------------------------------------------------------------------
__global__ __launch_bounds__(256) void zero_cnt_kernel(int* __restrict__ cnt) {
  int i = blockIdx.x * 256 + threadIdx.x;
  if (i < B_ * N_) cnt[i] = 0;
}

__global__ __launch_bounds__(256) void build_inv_kernel(const int* __restrict__ I,
                                                        const float* __restrict__ G,
                                                        int* __restrict__ cnt,
                                                        int* __restrict__ entI,
                                                        float* __restrict__ entG) {
  int idx = blockIdx.x * 256 + threadIdx.x;  // over B*E*K = 32768
  int be = idx >> 10;
  int k = idx & (K_ - 1);
  int b = be >> 3, e = be & 7;
  int tok = I[idx];
  float g = G[idx];
  int slot = atomicAdd(&cnt[b * N_ + tok], 1);
  entI[(b * N_ + tok) * E_ + slot] = (e << 16) | k;
  entG[(b * N_ + tok) * E_ + slot] = g;
}

// ---------------------------------------------------------------------------
// Down: per (b,e) gathered [1024 x 2048] @ WdT^T -> h[1024 x 128], relu, bf16.
// Block: 64x128 tile, BK=64, 4 waves of 32x64. MFMA 16x16x32 bf16.
// ---------------------------------------------------------------------------
__global__ __launch_bounds__(256) void down_mfma(const unsigned short* __restrict__ xbf,
                                                 const unsigned short* __restrict__ WdT,
                                                 const float* __restrict__ bd,
                                                 const int* __restrict__ I,
                                                 unsigned short* __restrict__ h) {
  __shared__ unsigned short As[64 * 72] __attribute__((aligned(16)));
  __shared__ unsigned short Bs[128 * 72] __attribute__((aligned(16)));
  __shared__ int s_tok[64];
  int be = blockIdx.x;
  int m0 = blockIdx.y * 64;
  int b = be >> 3, e = be & 7;
  int tid = threadIdx.x;
  if (tid < 64) s_tok[tid] = I[be * K_ + m0 + tid];
  __syncthreads();
  int lane = tid & 63, wave = tid >> 6;
  int l15 = lane & 15, quad = lane >> 4;
  int wrow = (wave >> 1) * 32, wcol = (wave & 1) * 64;

  const unsigned short* srcA[2];
  int dstA[2];
#pragma unroll
  for (int i = 0; i < 2; ++i) {
    int g = tid + 256 * i;
    int row = g >> 3, part = g & 7;
    srcA[i] = xbf + ((size_t)(b * N_ + s_tok[row])) * D_ + part * 8;
    dstA[i] = row * 72 + part * 8;
  }
  const unsigned short* Wde = WdT + (size_t)e * R_ * D_;
  const unsigned short* srcB[4];
  int dstB[4];
#pragma unroll
  for (int i = 0; i < 4; ++i) {
    int g = tid + 256 * i;
    int row = g >> 3, part = g & 7;
    srcB[i] = Wde + (size_t)row * D_ + part * 8;
    dstB[i] = row * 72 + part * 8;
  }

  f32x4 zv = {0.f, 0.f, 0.f, 0.f};
  f32x4 acc[2][4];
#pragma unroll
  for (int mi = 0; mi < 2; ++mi)
#pragma unroll
    for (int ni = 0; ni < 4; ++ni) acc[mi][ni] = zv;

  for (int d0 = 0; d0 < D_; d0 += 64) {
#pragma unroll
    for (int i = 0; i < 2; ++i)
      *(uint4*)&As[dstA[i]] = *(const uint4*)(srcA[i] + d0);
#pragma unroll
    for (int i = 0; i < 4; ++i)
      *(uint4*)&Bs[dstB[i]] = *(const uint4*)(srcB[i] + d0);
    __syncthreads();
#pragma unroll
    for (int ks = 0; ks < 64; ks += 32) {
      bf16x8 a[2], bb[4];
#pragma unroll
      for (int mi = 0; mi < 2; ++mi)
        a[mi] = *(const bf16x8*)&As[(wrow + mi * 16 + l15) * 72 + ks + quad * 8];
#pragma unroll
      for (int ni = 0; ni < 4; ++ni)
        bb[ni] = *(const bf16x8*)&Bs[(wcol + ni * 16 + l15) * 72 + ks + quad * 8];
#pragma unroll
      for (int mi = 0; mi < 2; ++mi)
#pragma unroll
        for (int ni = 0; ni < 4; ++ni)
          acc[mi][ni] = __builtin_amdgcn_mfma_f32_16x16x32_bf16(a[mi], bb[ni], acc[mi][ni], 0, 0, 0);
    }
    __syncthreads();
  }
#pragma unroll
  for (int mi = 0; mi < 2; ++mi) {
#pragma unroll
    for (int ni = 0; ni < 4; ++ni) {
      int col = wcol + ni * 16 + l15;
      float bias = bd[e * R_ + col];
#pragma unroll
      for (int r = 0; r < 4; ++r) {
        int mrow = m0 + wrow + mi * 16 + quad * 4 + r;
        float v = acc[mi][ni][r] + bias;
        h[((size_t)be * K_ + mrow) * R_ + col] = f2bf(v > 0.f ? v : 0.f);
      }
    }
  }
}

// ---------------------------------------------------------------------------
// Up, single launch over ALL (b,e) (4096 blocks, was 8 serialized launches of
// 512): h[128x128] @ WuT^T -> contrib[b,e,k, n0..n0+128) = acc + bu (f32).
// Pure coalesced write, no RMW, no races, no x re-read.
// ---------------------------------------------------------------------------
__global__ __launch_bounds__(256) void up_all_mfma(const unsigned short* __restrict__ WuT,
                                                   const float* __restrict__ bu,
                                                   const unsigned short* __restrict__ h,
                                                   float* __restrict__ contrib) {
  __shared__ unsigned short As[128 * 136] __attribute__((aligned(16)));
  __shared__ unsigned short Bs[128 * 136] __attribute__((aligned(16)));
  int ntile = blockIdx.x;   // 16
  int mtile = blockIdx.y;   // 8
  int be = blockIdx.z;      // 32
  int e = be & 7;
  int m0 = mtile * 128, n0 = ntile * 128;
  int tid = threadIdx.x;
  const unsigned short* hbe = h + ((size_t)be * K_ + m0) * R_;
  const unsigned short* Wue = WuT + ((size_t)e * D_ + n0) * R_;
#pragma unroll
  for (int i = 0; i < 8; ++i) {
    int g = tid + 256 * i;
    int row = g >> 4, part = g & 15;
    *(uint4*)&As[row * 136 + part * 8] = *(const uint4*)(hbe + (size_t)row * R_ + part * 8);
  }
#pragma unroll
  for (int i = 0; i < 8; ++i) {
    int g = tid + 256 * i;
    int row = g >> 4, part = g & 15;
    *(uint4*)&Bs[row * 136 + part * 8] = *(const uint4*)(Wue + (size_t)row * R_ + part * 8);
  }
  __syncthreads();

  int lane = tid & 63, wave = tid >> 6;
  int l15 = lane & 15, quad = lane >> 4;
  int wrow = (wave >> 1) * 64, wcol = (wave & 1) * 64;
  f32x4 zv = {0.f, 0.f, 0.f, 0.f};
  f32x4 acc[4][4];
#pragma unroll
  for (int mi = 0; mi < 4; ++mi)
#pragma unroll
    for (int ni = 0; ni < 4; ++ni) acc[mi][ni] = zv;

#pragma unroll
  for (int ks = 0; ks < 128; ks += 32) {
    bf16x8 a[4], bb[4];
#pragma unroll
    for (int mi = 0; mi < 4; ++mi)
      a[mi] = *(const bf16x8*)&As[(wrow + mi * 16 + l15) * 136 + ks + quad * 8];
#pragma unroll
    for (int ni = 0; ni < 4; ++ni)
      bb[ni] = *(const bf16x8*)&Bs[(wcol + ni * 16 + l15) * 136 + ks + quad * 8];
#pragma unroll
    for (int mi = 0; mi < 4; ++mi)
#pragma unroll
      for (int ni = 0; ni < 4; ++ni)
        acc[mi][ni] = __builtin_amdgcn_mfma_f32_16x16x32_bf16(a[mi], bb[ni], acc[mi][ni], 0, 0, 0);
  }

#pragma unroll
  for (int mi = 0; mi < 4; ++mi) {
#pragma unroll
    for (int r = 0; r < 4; ++r) {
      int row = wrow + mi * 16 + quad * 4 + r;
      float* outr = contrib + ((size_t)be * K_ + m0 + row) * D_ + n0;
#pragma unroll
      for (int ni = 0; ni < 4; ++ni) {
        int col = wcol + ni * 16 + l15;
        outr[col] = acc[mi][ni][r] + bu[e * D_ + n0 + col];
      }
    }
  }
}

// ---------------------------------------------------------------------------
// Combine (gather): one block per token (b,n).
// out = residual + (sum g)*x + sum_i g_i * contrib[b,e_i,k_i,:].
// Replaces init_out + the scatter-RMW. Each contrib row read exactly once.
// ---------------------------------------------------------------------------
__global__ __launch_bounds__(256) void combine_kernel(const float* __restrict__ x,
                                                      const float* __restrict__ residual,
                                                      const float* __restrict__ contrib,
                                                      const int* __restrict__ cnt,
                                                      const int* __restrict__ entI,
                                                      const float* __restrict__ entG,
                                                      float* __restrict__ out) {
  __shared__ int s_c;
  __shared__ int s_ei[E_];
  __shared__ float s_gv[E_];
  int bn = blockIdx.x;           // b*N + n
  int tid = threadIdx.x;
  if (tid == 0) s_c = cnt[bn];
  if (tid < E_) {
    s_ei[tid] = entI[bn * E_ + tid];
    s_gv[tid] = entG[bn * E_ + tid];
  }
  __syncthreads();
  int c = s_c;

  size_t rowoff = (size_t)bn * D_ + tid * 8;
  float4 r0 = *(const float4*)(residual + rowoff);
  float4 r1 = *(const float4*)(residual + rowoff + 4);
  float4 xv0 = *(const float4*)(x + rowoff);
  float4 xv1 = *(const float4*)(x + rowoff + 4);

  float s = 0.f;
  float4 a0 = {0.f, 0.f, 0.f, 0.f}, a1 = {0.f, 0.f, 0.f, 0.f};
  int b = bn >> 12;
  for (int i = 0; i < c; ++i) {
    int ei = s_ei[i];
    float g = s_gv[i];
    s += g;
    int e = ei >> 16, k = ei & 0xFFFF;
    const float* cr = contrib + ((size_t)(b * E_ + e) * K_ + k) * D_ + tid * 8;
    float4 c0 = *(const float4*)(cr);
    float4 c1 = *(const float4*)(cr + 4);
    a0.x += g * c0.x; a0.y += g * c0.y; a0.z += g * c0.z; a0.w += g * c0.w;
    a1.x += g * c1.x; a1.y += g * c1.y; a1.z += g * c1.z; a1.w += g * c1.w;
  }
  float4 o0, o1;
  o0.x = r0.x + s * xv0.x + a0.x;
  o0.y = r0.y + s * xv0.y + a0.y;
  o0.z = r0.z + s * xv0.z + a0.z;
  o0.w = r0.w + s * xv0.w + a0.w;
  o1.x = r1.x + s * xv1.x + a1.x;
  o1.y = r1.y + s * xv1.y + a1.y;
  o1.z = r1.z + s * xv1.z + a1.z;
  o1.w = r1.w + s * xv1.w + a1.w;
  *(float4*)(out + rowoff) = o0;
  *(float4*)(out + rowoff + 4) = o1;
}

// ---------------------------------------------------------------------------
extern "C" void kernel_launch(void* const* d_in, const int* in_sizes, int n_in,
                              void* d_out, int out_size, void* d_ws, size_t ws_size,
                              hipStream_t stream) {
  const float* x        = (const float*)d_in[0];
  const float* residual = (const float*)d_in[1];
  const float* Wg       = (const float*)d_in[2];
  const float* bg       = (const float*)d_in[3];
  const float* Wd       = (const float*)d_in[4];
  const float* bd       = (const float*)d_in[5];
  const float* Wu       = (const float*)d_in[6];
  const float* bu       = (const float*)d_in[7];
  float* out = (float*)d_out;

  // ws layout (all region sizes 256B-multiples), total ~338 MB:
  // logitsT f32[B*E*N] | I i32[B*E*K] | G f32[B*E*K] | xbf bf16[B*N*D]
  // | WdT bf16[E*R*D] | WuT bf16[E*D*R] | h bf16[B*E*K*R]
  // | cnt i32[B*N] | entI i32[B*N*E] | entG f32[B*N*E] | contrib f32[B*E*K*D]
  char* p = (char*)d_ws;
  float* logitsT = (float*)p;            p += (size_t)B_ * E_ * N_ * 4;
  int* Ibuf = (int*)p;                   p += (size_t)B_ * E_ * K_ * 4;
  float* Gbuf = (float*)p;               p += (size_t)B_ * E_ * K_ * 4;
  unsigned short* xbf = (unsigned short*)p;  p += (size_t)B_ * N_ * D_ * 2;
  unsigned short* WdT = (unsigned short*)p;  p += (size_t)E_ * R_ * D_ * 2;
  unsigned short* WuT = (unsigned short*)p;  p += (size_t)E_ * D_ * R_ * 2;
  unsigned short* hbuf = (unsigned short*)p; p += (size_t)B_ * E_ * K_ * R_ * 2;
  int* cnt = (int*)p;                    p += (size_t)B_ * N_ * 4;
  int* entI = (int*)p;                   p += (size_t)B_ * N_ * E_ * 4;
  float* entG = (float*)p;               p += (size_t)B_ * N_ * E_ * 4;
  float* contrib = (float*)p;

  gate_kernel<<<B_ * N_ / 16, 1024, 0, stream>>>(x, Wg, bg, logitsT, xbf);
  topk_kernel<<<B_ * E_, 1024, 0, stream>>>(logitsT, Ibuf, Gbuf);
  cvt_wd_kernel<<<E_ * D_ * R_ / 256, 256, 0, stream>>>(Wd, WdT);
  cvt_wu_kernel<<<E_ * D_ * R_ / 256, 256, 0, stream>>>(Wu, WuT);
  zero_cnt_kernel<<<(B_ * N_ + 255) / 256, 256, 0, stream>>>(cnt);
  build_inv_kernel<<<B_ * E_ * K_ / 256, 256, 0, stream>>>(Ibuf, Gbuf, cnt, entI, entG);
  down_mfma<<<dim3(B_ * E_, K_ / 64), 256, 0, stream>>>(xbf, WdT, bd, Ibuf, hbuf);
  up_all_mfma<<<dim3(D_ / 128, K_ / 128, B_ * E_), 256, 0, stream>>>(WuT, bu, hbuf, contrib);
  combine_kernel<<<B_ * N_, 256, 0, stream>>>(x, residual, contrib, cnt, entI, entG, out);
}